// Round 18
// baseline (152.301 us; speedup 1.0000x reference)
//
#include <hip/hip_runtime.h>

typedef unsigned short u16;
typedef unsigned int u32;
typedef __bf16 bf16x8 __attribute__((ext_vector_type(8)));
typedef float f32x4 __attribute__((ext_vector_type(4)));

#define B_SZ 4
#define L_SZ 2048
#define D_SZ 512
#define H_SZ 8
#define E_SZ 64

// log2(e)/8 folded into Q projection so softmax uses native v_exp_f32 (2^x)
#define Q_SCALE 0.18033688011112042f

// ---------------- workspace layout (bytes) ----------------
#define WS_FLAG   0
#define WS_WPACK  1024                     // 1536x512 bf16 = 1572864 (grouped-eperm)
#define WS_BPACK  (WS_WPACK + 1572864)     // 1536 f32 = 6144
#define WS_WOUT   (WS_BPACK + 6144)        // 512x512 bf16 = 524288 (grouped-eperm)
#define WS_QBF    (WS_WOUT + 524288)       // 8192x512 bf16 = 8388608 (grouped-eperm)
#define WS_Q      (WS_QBF + 8388608)       // [b][h][l][eperm] bf16 = 8388608
#define WS_K      (WS_Q + 8388608)
#define WS_V      (WS_K + 8388608)         // [row][gperm(hd)] bf16 = 8388608
#define WS_STATS  (WS_V + 8388608)         // 4*8*2048 float = 262144

static __device__ __forceinline__ u16 f2bf(float f) {
  unsigned int u = __float_as_uint(f);
  u += 0x7FFFu + ((u >> 16) & 1u);
  return (u16)(u >> 16);
}

static __device__ __forceinline__ float fexp2(float x) {
  return __builtin_amdgcn_exp2f(x);
}

union FragU { bf16x8 v; uint4 u4; unsigned long long ul[2]; };

// grouped-eperm: within each 32-col group, 16B chunk lg holds
// elements [lg*4..+3] then [16+lg*4..+3]  => one MFMA fragment = one 16B chunk
static __device__ __forceinline__ int gperm(int d) {
  int t = d & 31;
  return (d & ~31) | ((t & 12) << 1) | ((t & 16) >> 2) | (t & 3);
}

// fragment from PERMUTED 64-elem rows (one 16B load); half = k0/32
static __device__ __forceinline__ bf16x8 qfrag(const u16* __restrict__ Qp,
                                               int row, int half, int lg) {
  FragU f;
  f.u4 = *reinterpret_cast<const uint4*>(
      (const char*)Qp + (size_t)row * 128 + (half << 6) + (lg << 4));
  return f.v;
}

static __device__ __forceinline__ void gload_lds16(const void* g, void* l) {
  __builtin_amdgcn_global_load_lds(
      (const __attribute__((address_space(1))) void*)g,
      (__attribute__((address_space(3))) void*)l, 16, 0, 0);
}

// Stage NCHUNK/8 rows x 128B of permuted K into LDS, XOR-swizzled at 16B-chunk
// granularity (chunk ^= (row&7)) via pre-swizzled GLOBAL source (dest linear).
template<int NT, int NCHUNK>
static __device__ __forceinline__ void stage_ktile(const u16* __restrict__ Kh, int kb0,
                                                   char* tile, int tid) {
  int wbase = (tid & ~63) * 16;             // wave-uniform LDS base
#pragma unroll
  for (int i = 0; i < NCHUNK / NT; i++) {
    int cl = tid + i * NT;                  // 16B chunk id
    int r = cl >> 3, c = cl & 7;
    const char* g = (const char*)Kh + (size_t)(kb0 + r) * 128 + ((c ^ (r & 7)) << 4);
    gload_lds16(g, tile + wbase + i * NT * 16);
  }
}

// read one fragment (16 rows at c*16, k-group `half`) from a swizzled LDS tile
static __device__ __forceinline__ bf16x8 lds_frag(const char* tile, int c, int half,
                                                  int lr, int lg) {
  int r = c * 16 + lr;
  int off = ((half << 6) | (lg << 4)) ^ ((r & 7) << 4);
  FragU f;
  f.u4 = *reinterpret_cast<const uint4*>(tile + r * 128 + off);
  return f.v;
}

// ---------------- mask dtype detection (parallel) ----------------
__global__ __launch_bounds__(256) void kdetect(const unsigned int* __restrict__ w,
                                               int* __restrict__ flag) {
  int fB = 0, fF = 0;
  for (int i = blockIdx.x * blockDim.x + threadIdx.x; i < 262144;
       i += gridDim.x * blockDim.x) {
    unsigned int v = w[i];
    if (v == 0x3F800000u) fF = 1;
    else if (v > 1u) fB = 1;
  }
  if (__any(fB)) { if ((threadIdx.x & 63) == 0) atomicOr(&flag[0], 1); }
  if (__any(fF)) { if ((threadIdx.x & 63) == 0) atomicOr(&flag[1], 1); }
}

// ---------------- pack: weights (perm + bf16 + gperm) AND q cast (fused) ----------
__global__ __launch_bounds__(256) void kpack(const float* __restrict__ q,
                                             const float* __restrict__ w_in,
                                             const float* __restrict__ b_in,
                                             const float* __restrict__ w_out,
                                             u16* __restrict__ Wpack, float* __restrict__ bpack,
                                             u16* __restrict__ Wout, u16* __restrict__ qbf) {
  const int T0 = 1536 * 512;           // Wpack elements
  const int T1 = T0 + 512 * 512;       // Wout elements
  const int T2 = T1 + 1536;            // bpack
  const int T3 = T2 + 524288;          // qbf 16B-chunks (8 elems each)
  for (int i = blockIdx.x * blockDim.x + threadIdx.x; i < T3; i += gridDim.x * blockDim.x) {
    if (i < T0) {
      int n = i >> 9, d = i & 511;
      int sel = n >> 9, idx = n & 511;
      int h = idx >> 6, e = idx & 63;
      int row = h * 192 + e * 3 + sel;   // in_weight.reshape(H,64,3,D) interleave
      float v = w_in[row * 512 + d];
      if (sel == 0) v *= Q_SCALE;
      Wpack[(size_t)n * 512 + gperm(d)] = f2bf(v);
    } else if (i < T1) {
      int j = i - T0;
      int n = j >> 9, d = j & 511;
      Wout[(size_t)n * 512 + gperm(d)] = f2bf(w_out[j]);
    } else if (i < T2) {
      int n = i - T1;
      int sel = n >> 9, idx = n & 511;
      int h = idx >> 6, e = idx & 63;
      int row = h * 192 + e * 3 + sel;
      float v = b_in[row];
      if (sel == 0) v *= Q_SCALE;
      bpack[n] = v;
    } else {
      int j = i - T2;                     // qbf chunk id
      int row = j >> 6, c = j & 63;
      int g = c >> 2, lg = c & 3;
      const float* src = q + (size_t)row * 512 + g * 32 + lg * 4;
      float4 v0 = *reinterpret_cast<const float4*>(src);
      float4 v1 = *reinterpret_cast<const float4*>(src + 16);
      u32 w0 = f2bf(v0.x) | ((u32)f2bf(v0.y) << 16);
      u32 w1 = f2bf(v0.z) | ((u32)f2bf(v0.w) << 16);
      u32 w2 = f2bf(v1.x) | ((u32)f2bf(v1.y) << 16);
      u32 w3 = f2bf(v1.z) | ((u32)f2bf(v1.w) << 16);
      uint4 out = {w0, w1, w2, w3};
      *reinterpret_cast<uint4*>(qbf + (size_t)row * 512 + c * 8) = out;
    }
  }
}

// ---------------- stage one 128x64-elem K-tile pair (A and B) into LDS ----------
static __device__ __forceinline__ void stage_tile(const u16* __restrict__ A,
                                                  const u16* __restrict__ Bw,
                                                  int m0, int n0, int t,
                                                  char* tA, char* tB, int tid) {
  int w64 = tid & ~63;                      // wave base (uniform per wave)
#pragma unroll
  for (int i = 0; i < 4; i++) {
    int cl = tid + i * 256;                 // 16B chunk id, 0..1023
    int r = cl >> 3, c = cl & 7;
    size_t gofs = (size_t)r * 1024 + t * 128 + ((c ^ (r & 7)) << 4);
    gload_lds16((const char*)A + (size_t)m0 * 1024 + gofs, tA + (i * 256 + w64) * 16);
    gload_lds16((const char*)Bw + (size_t)n0 * 1024 + gofs, tB + (i * 256 + w64) * 16);
  }
}

// ---------------- tiled GEMM: C[M x N] = A[M x 512] @ B[N x 512]^T ----------------
// MODE 0: QKV projection epilogue (split Q/K/V, bf16, bias from bpack)
// MODE 1: out projection epilogue (f32 + bias)
template<int MODE>
__global__ __launch_bounds__(256) void kgemm(const u16* __restrict__ A,
                                             const u16* __restrict__ Bw,
                                             const float* __restrict__ bias,
                                             u16* __restrict__ Qb, u16* __restrict__ Kb,
                                             u16* __restrict__ Vb, float* __restrict__ outp) {
  __shared__ __align__(128) char tA[2][16384], tB[2][16384];
  int tid = threadIdx.x;
  int w = tid >> 6, lane = tid & 63;
  int lr = lane & 15, lg = lane >> 4;
  int m0 = blockIdx.x * 128, n0 = blockIdx.y * 128;
  int wr = w >> 1, wc = w & 1;

  f32x4 acc[4][4] = {};

  stage_tile(A, Bw, m0, n0, 0, tA[0], tB[0], tid);
  __syncthreads();
#pragma unroll 1
  for (int t = 0; t < 8; t++) {
    if (t < 7) stage_tile(A, Bw, m0, n0, t + 1, tA[(t + 1) & 1], tB[(t + 1) & 1], tid);
    const char* mA = tA[t & 1] + wr * 64 * 128;
    const char* mB = tB[t & 1] + wc * 64 * 128;
#pragma unroll
    for (int gg = 0; gg < 2; gg++) {
      bf16x8 af[4], bf_[4];
#pragma unroll
      for (int i = 0; i < 4; i++) af[i] = lds_frag(mA, i, gg, lr, lg);
#pragma unroll
      for (int j = 0; j < 4; j++) bf_[j] = lds_frag(mB, j, gg, lr, lg);
#pragma unroll
      for (int i = 0; i < 4; i++)
#pragma unroll
        for (int j = 0; j < 4; j++)
          acc[i][j] = __builtin_amdgcn_mfma_f32_16x16x32_bf16(af[i], bf_[j], acc[i][j], 0, 0, 0);
    }
    __syncthreads();
  }

#pragma unroll
  for (int j = 0; j < 4; j++) {
    int col = n0 + wc * 64 + j * 16 + lr;
    float bb = bias[col];
#pragma unroll
    for (int i = 0; i < 4; i++) {
#pragma unroll
      for (int jj = 0; jj < 4; jj++) {
        int row = m0 + wr * 64 + i * 16 + lg * 4 + jj;
        float val = acc[i][j][jj] + bb;
        if (MODE == 1) {
          outp[(size_t)row * 512 + col] = val;
        } else {
          u16 bv = f2bf(val);
          int b = row >> 11, l = row & 2047;
          if (col < 512) {
            int h = col >> 6, e = col & 63;
            Qb[((((size_t)(b * 8 + h)) << 11) + l) * 64 + gperm(e)] = bv;
          } else if (col < 1024) {
            int c2 = col - 512, h = c2 >> 6, e = c2 & 63;
            Kb[((((size_t)(b * 8 + h)) << 11) + l) * 64 + gperm(e)] = bv;
          } else {
            Vb[(size_t)row * 512 + gperm(col - 1024)] = bv;
          }
        }
      }
    }
  }
}

// ---------------- per-row softmax denom, swapped operands (D[k][q]) ----------------
// 4 waves x 32 q = 128 q rows/block; k-tile 64 rows, LDS 2x8KB; (256,4) = only
// spill-safe bound (gfx950 occupancy steps at 64 VGPR — measured R15/R16).
__global__ __launch_bounds__(256, 4) void kstats(const u16* __restrict__ Qb,
                                                 const u16* __restrict__ Kb,
                                                 float* __restrict__ stats) {
  __shared__ __align__(128) char tile[2][8192];
  int bh = blockIdx.x;
  int tid = threadIdx.x;
  int w = tid >> 6, lane = tid & 63;
  int lr = lane & 15, lg = lane >> 4;
  int q0 = blockIdx.y * 128 + w * 32;
  const u16* Qp = Qb + (size_t)bh * L_SZ * E_SZ;
  const u16* Kp = Kb + (size_t)bh * L_SZ * E_SZ;

  bf16x8 bq0 = qfrag(Qp, q0 + lr, 0, lg);
  bf16x8 bq1 = qfrag(Qp, q0 + lr, 1, lg);
  bf16x8 bq2 = qfrag(Qp, q0 + 16 + lr, 0, lg);
  bf16x8 bq3 = qfrag(Qp, q0 + 16 + lr, 1, lg);
  float s0 = 0.0f, s1 = 0.0f;

  stage_ktile<256, 512>(Kp, 0, tile[0], tid);
  __syncthreads();
#pragma unroll 1
  for (int t = 0; t < 32; t++) {
    if (t + 1 < 32) stage_ktile<256, 512>(Kp, (t + 1) * 64, tile[(t + 1) & 1], tid);
    const char* tl = tile[t & 1];
#pragma unroll
    for (int c = 0; c < 4; c++) {
      bf16x8 a0 = lds_frag(tl, c, 0, lr, lg);
      bf16x8 a1 = lds_frag(tl, c, 1, lr, lg);
      f32x4 d0 = {0.f, 0.f, 0.f, 0.f}, d1 = {0.f, 0.f, 0.f, 0.f};
      d0 = __builtin_amdgcn_mfma_f32_16x16x32_bf16(a0, bq0, d0, 0, 0, 0);
      d0 = __builtin_amdgcn_mfma_f32_16x16x32_bf16(a1, bq1, d0, 0, 0, 0);
      d1 = __builtin_amdgcn_mfma_f32_16x16x32_bf16(a0, bq2, d1, 0, 0, 0);
      d1 = __builtin_amdgcn_mfma_f32_16x16x32_bf16(a1, bq3, d1, 0, 0, 0);
      s0 += fexp2(d0[0]) + fexp2(d0[1]) + fexp2(d0[2]) + fexp2(d0[3]);
      s1 += fexp2(d1[0]) + fexp2(d1[1]) + fexp2(d1[2]) + fexp2(d1[3]);
    }
    __syncthreads();
  }
  s0 += __shfl_xor(s0, 16); s0 += __shfl_xor(s0, 32);
  s1 += __shfl_xor(s1, 16); s1 += __shfl_xor(s1, 32);
  if (lane < 16) {
    stats[(size_t)bh * L_SZ + q0 + lr] = 1.0f / s0;
    stats[(size_t)bh * L_SZ + q0 + 16 + lr] = 1.0f / s1;
  }
}

// ---------------- masks: 64 q/wave (4 q-sets), k-tile 64, LDS 2x8KB ----------------
// Doubling q-per-wave again halves staging+barrier cost per output (the R12 win
// mechanism). Q frags loaded in-loop (no prefetch regs) to fit the 128-VGPR
// budget at (256,4). All accumulator/bitmask accesses STATIC (rule #20).
#define KM_PACKMASK(BITS, QOFS)                                                  \
  {                                                                              \
    size_t moff = mb + (size_t)(q0 + (QOFS) + lr) * L_SZ + kb0;                  \
    if (mode == 0) {                                                             \
      _Pragma("unroll")                                                          \
      for (int c = 0; c < 4; c++) {                                              \
        int4 mi = *reinterpret_cast<const int4*>((const int*)mask + moff + c * 16 + lg * 4); \
        BITS |= (mi.x ? 1u : 0u) << (c * 4);                                     \
        BITS |= (mi.y ? 1u : 0u) << (c * 4 + 1);                                 \
        BITS |= (mi.z ? 1u : 0u) << (c * 4 + 2);                                 \
        BITS |= (mi.w ? 1u : 0u) << (c * 4 + 3);                                 \
      }                                                                          \
    } else if (mode == 1) {                                                      \
      _Pragma("unroll")                                                          \
      for (int c = 0; c < 4; c++) {                                              \
        u32 mw = *reinterpret_cast<const u32*>((const unsigned char*)mask + moff + c * 16 + lg * 4); \
        BITS |= ((mw & 0x000000FFu) ? 1u : 0u) << (c * 4);                       \
        BITS |= ((mw & 0x0000FF00u) ? 1u : 0u) << (c * 4 + 1);                   \
        BITS |= ((mw & 0x00FF0000u) ? 1u : 0u) << (c * 4 + 2);                   \
        BITS |= ((mw & 0xFF000000u) ? 1u : 0u) << (c * 4 + 3);                   \
      }                                                                          \
    } else {                                                                     \
      _Pragma("unroll")                                                          \
      for (int c = 0; c < 4; c++) {                                              \
        float4 mf = *reinterpret_cast<const float4*>((const float*)mask + moff + c * 16 + lg * 4); \
        BITS |= ((mf.x != 0.f) ? 1u : 0u) << (c * 4);                            \
        BITS |= ((mf.y != 0.f) ? 1u : 0u) << (c * 4 + 1);                        \
        BITS |= ((mf.z != 0.f) ? 1u : 0u) << (c * 4 + 2);                        \
        BITS |= ((mf.w != 0.f) ? 1u : 0u) << (c * 4 + 3);                        \
      }                                                                          \
    }                                                                            \
  }

#define KM_EPILOGUE(PACC, QOFS, BITS)                                            \
  {                                                                              \
    int q = q0 + (QOFS) + lr;                                                    \
    float* mrow = mbase_out + (size_t)q * L_SZ + kb0;                            \
    _Pragma("unroll")                                                            \
    for (int c = 0; c < 4; c++) {                                                \
      int kk = c * 16 + lg * 4;                                                  \
      f32x4 v = PACC[c];                                                         \
      if ((BITS >> (c * 4 + 0)) & 1u) v[0] = 0.f;                                \
      if ((BITS >> (c * 4 + 1)) & 1u) v[1] = 0.f;                                \
      if ((BITS >> (c * 4 + 2)) & 1u) v[2] = 0.f;                                \
      if ((BITS >> (c * 4 + 3)) & 1u) v[3] = 0.f;                                \
      *reinterpret_cast<f32x4*>(mrow + kk) = v;                                  \
    }                                                                            \
  }

__global__ __launch_bounds__(256, 4) void kmasks(const u16* __restrict__ Qb,
                                                 const u16* __restrict__ Kb,
                                                 const float* __restrict__ stats,
                                                 const void* __restrict__ mask,
                                                 const int* __restrict__ flag,
                                                 float* __restrict__ outp) {
  __shared__ __align__(128) char tile[2][8192];
  int b = blockIdx.z;
  int tid = threadIdx.x;
  int w = tid >> 6, lane = tid & 63;
  int lr = lane & 15, lg = lane >> 4;
  int q0 = blockIdx.y * 256 + w * 64;
  int kb0 = blockIdx.x * 64;
  int mode = flag[0] ? 1 : (flag[1] ? 2 : 0);
  const size_t LE = (size_t)L_SZ * E_SZ;
  size_t mb = (size_t)b * L_SZ * L_SZ;

  f32x4 P0[4] = {}, P1[4] = {}, P2[4] = {}, P3[4] = {};

  // prologue: stage head-0 K tile; mask bits (overlaps staging)
  stage_ktile<256, 512>(Kb + (size_t)(b * 8) * LE, kb0, tile[0], tid);
  u32 bits0 = 0, bits1 = 0, bits2 = 0, bits3 = 0;
  KM_PACKMASK(bits0, 0)
  KM_PACKMASK(bits1, 16)
  KM_PACKMASK(bits2, 32)
  KM_PACKMASK(bits3, 48)
  __syncthreads();

#pragma unroll 1
  for (int h = 0; h < 8; h++) {
    if (h + 1 < 8)
      stage_ktile<256, 512>(Kb + (size_t)(b * 8 + h + 1) * LE, kb0, tile[(h + 1) & 1], tid);
    const u16* Qp = Qb + (size_t)(b * 8 + h) * LE;
    const float* st = stats + (size_t)(b * 8 + h) * L_SZ;
    bf16x8 bq0 = qfrag(Qp, q0 + lr, 0, lg);
    bf16x8 bq1 = qfrag(Qp, q0 + lr, 1, lg);
    bf16x8 bq2 = qfrag(Qp, q0 + 16 + lr, 0, lg);
    bf16x8 bq3 = qfrag(Qp, q0 + 16 + lr, 1, lg);
    bf16x8 bq4 = qfrag(Qp, q0 + 32 + lr, 0, lg);
    bf16x8 bq5 = qfrag(Qp, q0 + 32 + lr, 1, lg);
    bf16x8 bq6 = qfrag(Qp, q0 + 48 + lr, 0, lg);
    bf16x8 bq7 = qfrag(Qp, q0 + 48 + lr, 1, lg);
    float rr0 = st[q0 + lr];
    float rr1 = st[q0 + 16 + lr];
    float rr2 = st[q0 + 32 + lr];
    float rr3 = st[q0 + 48 + lr];
    const char* tl = tile[h & 1];
#pragma unroll
    for (int c = 0; c < 4; c++) {
      bf16x8 a0 = lds_frag(tl, c, 0, lr, lg);
      bf16x8 a1 = lds_frag(tl, c, 1, lr, lg);
      {
        f32x4 d = {0.f, 0.f, 0.f, 0.f};
        d = __builtin_amdgcn_mfma_f32_16x16x32_bf16(a0, bq0, d, 0, 0, 0);
        d = __builtin_amdgcn_mfma_f32_16x16x32_bf16(a1, bq1, d, 0, 0, 0);
#pragma unroll
        for (int j = 0; j < 4; j++) P0[c][j] += fexp2(d[j]) * rr0;
      }
      {
        f32x4 d = {0.f, 0.f, 0.f, 0.f};
        d = __builtin_amdgcn_mfma_f32_16x16x32_bf16(a0, bq2, d, 0, 0, 0);
        d = __builtin_amdgcn_mfma_f32_16x16x32_bf16(a1, bq3, d, 0, 0, 0);
#pragma unroll
        for (int j = 0; j < 4; j++) P1[c][j] += fexp2(d[j]) * rr1;
      }
      {
        f32x4 d = {0.f, 0.f, 0.f, 0.f};
        d = __builtin_amdgcn_mfma_f32_16x16x32_bf16(a0, bq4, d, 0, 0, 0);
        d = __builtin_amdgcn_mfma_f32_16x16x32_bf16(a1, bq5, d, 0, 0, 0);
#pragma unroll
        for (int j = 0; j < 4; j++) P2[c][j] += fexp2(d[j]) * rr2;
      }
      {
        f32x4 d = {0.f, 0.f, 0.f, 0.f};
        d = __builtin_amdgcn_mfma_f32_16x16x32_bf16(a0, bq6, d, 0, 0, 0);
        d = __builtin_amdgcn_mfma_f32_16x16x32_bf16(a1, bq7, d, 0, 0, 0);
#pragma unroll
        for (int j = 0; j < 4; j++) P3[c][j] += fexp2(d[j]) * rr3;
      }
    }
    __syncthreads();
  }

  float* mbase_out = outp + (size_t)B_SZ * L_SZ * D_SZ + (size_t)b * L_SZ * L_SZ;
  KM_EPILOGUE(P0, 0, bits0)
  KM_EPILOGUE(P1, 16, bits1)
  KM_EPILOGUE(P2, 32, bits2)
  KM_EPILOGUE(P3, 48, bits3)
}

extern "C" void kernel_launch(void* const* d_in, const int* in_sizes, int n_in,
                              void* d_out, int out_size, void* d_ws, size_t ws_size,
                              hipStream_t stream) {
  (void)in_sizes; (void)n_in; (void)out_size; (void)ws_size;
  const float* q     = (const float*)d_in[0];
  const void*  mask  = d_in[1];
  const float* w_in  = (const float*)d_in[2];
  const float* b_in  = (const float*)d_in[3];
  const float* w_out = (const float*)d_in[4];
  const float* b_out = (const float*)d_in[5];
  float* outp = (float*)d_out;
  char* ws = (char*)d_ws;

  int*    flag  = (int*)(ws + WS_FLAG);
  u16*    Wpack = (u16*)(ws + WS_WPACK);
  float*  bpack = (float*)(ws + WS_BPACK);
  u16*    Wout  = (u16*)(ws + WS_WOUT);
  u16*    qbf   = (u16*)(ws + WS_QBF);
  u16*    Qb    = (u16*)(ws + WS_Q);
  u16*    Kb    = (u16*)(ws + WS_K);
  u16*    Vb    = (u16*)(ws + WS_V);
  float*  stats = (float*)(ws + WS_STATS);

  hipMemsetAsync(flag, 0, 16, stream);
  hipLaunchKernelGGL(kdetect, dim3(256), dim3(256), 0, stream, (const unsigned int*)mask, flag);
  hipLaunchKernelGGL(kpack, dim3(3072), dim3(256), 0, stream, q, w_in, b_in, w_out,
                     Wpack, bpack, Wout, qbf);
  hipLaunchKernelGGL((kgemm<0>), dim3(64, 12), dim3(256), 0, stream,
                     qbf, Wpack, bpack, Qb, Kb, Vb, (float*)nullptr);
  hipLaunchKernelGGL((kgemm<1>), dim3(64, 4), dim3(256), 0, stream,
                     Vb, Wout, b_out, (u16*)nullptr, (u16*)nullptr, (u16*)nullptr, outp);
  hipLaunchKernelGGL(kstats, dim3(32, 16), dim3(256), 0, stream, Qb, Kb, stats);
  hipLaunchKernelGGL(kmasks, dim3(32, 8, 4), dim3(256), 0, stream, Qb, Kb, stats, mask, flag, outp);
}

// Round 19
// 136.730 us; speedup vs baseline: 1.1139x; 1.1139x over previous
//
#include <hip/hip_runtime.h>

typedef unsigned short u16;
typedef unsigned int u32;
typedef __bf16 bf16x8 __attribute__((ext_vector_type(8)));
typedef float f32x4 __attribute__((ext_vector_type(4)));

#define B_SZ 4
#define L_SZ 2048
#define D_SZ 512
#define H_SZ 8
#define E_SZ 64

// log2(e)/8 folded into Q projection so softmax uses native v_exp_f32 (2^x)
#define Q_SCALE 0.18033688011112042f

// ---------------- workspace layout (bytes) ----------------
#define WS_FLAG   0
#define WS_WPACK  1024                     // 1536x512 bf16 = 1572864 (grouped-eperm)
#define WS_BPACK  (WS_WPACK + 1572864)     // 1536 f32 = 6144
#define WS_WOUT   (WS_BPACK + 6144)        // 512x512 bf16 = 524288 (grouped-eperm)
#define WS_QBF    (WS_WOUT + 524288)       // 8192x512 bf16 = 8388608 (grouped-eperm)
#define WS_Q      (WS_QBF + 8388608)       // [b][h][l][eperm] bf16 = 8388608
#define WS_K      (WS_Q + 8388608)
#define WS_V      (WS_K + 8388608)         // [row][gperm(hd)] bf16 = 8388608
#define WS_STATS  (WS_V + 8388608)         // 4*8*2048 float = 262144

static __device__ __forceinline__ u16 f2bf(float f) {
  unsigned int u = __float_as_uint(f);
  u += 0x7FFFu + ((u >> 16) & 1u);
  return (u16)(u >> 16);
}

static __device__ __forceinline__ float fexp2(float x) {
  return __builtin_amdgcn_exp2f(x);
}

union FragU { bf16x8 v; uint4 u4; unsigned long long ul[2]; };

// grouped-eperm: within each 32-col group, 16B chunk lg holds
// elements [lg*4..+3] then [16+lg*4..+3]  => one MFMA fragment = one 16B chunk
static __device__ __forceinline__ int gperm(int d) {
  int t = d & 31;
  return (d & ~31) | ((t & 12) << 1) | ((t & 16) >> 2) | (t & 3);
}

// fragment from PERMUTED 64-elem rows (one 16B load); half = k0/32
static __device__ __forceinline__ bf16x8 qfrag(const u16* __restrict__ Qp,
                                               int row, int half, int lg) {
  FragU f;
  f.u4 = *reinterpret_cast<const uint4*>(
      (const char*)Qp + (size_t)row * 128 + (half << 6) + (lg << 4));
  return f.v;
}

static __device__ __forceinline__ void gload_lds16(const void* g, void* l) {
  __builtin_amdgcn_global_load_lds(
      (const __attribute__((address_space(1))) void*)g,
      (__attribute__((address_space(3))) void*)l, 16, 0, 0);
}

// Stage NCHUNK/8 rows x 128B of permuted K into LDS, XOR-swizzled at 16B-chunk
// granularity (chunk ^= (row&7)) via pre-swizzled GLOBAL source (dest linear).
template<int NT, int NCHUNK>
static __device__ __forceinline__ void stage_ktile(const u16* __restrict__ Kh, int kb0,
                                                   char* tile, int tid) {
  int wbase = (tid & ~63) * 16;             // wave-uniform LDS base
#pragma unroll
  for (int i = 0; i < NCHUNK / NT; i++) {
    int cl = tid + i * NT;                  // 16B chunk id
    int r = cl >> 3, c = cl & 7;
    const char* g = (const char*)Kh + (size_t)(kb0 + r) * 128 + ((c ^ (r & 7)) << 4);
    gload_lds16(g, tile + wbase + i * NT * 16);
  }
}

// read one fragment (16 rows at c*16, k-group `half`) from a swizzled LDS tile
static __device__ __forceinline__ bf16x8 lds_frag(const char* tile, int c, int half,
                                                  int lr, int lg) {
  int r = c * 16 + lr;
  int off = ((half << 6) | (lg << 4)) ^ ((r & 7) << 4);
  FragU f;
  f.u4 = *reinterpret_cast<const uint4*>(tile + r * 128 + off);
  return f.v;
}

// ---------------- cast q -> bf16 grouped-eperm + fused mask dtype detection ------
// (kdetect merged: first 262144 threads also classify one mask word each)
__global__ __launch_bounds__(256) void kcast(const float* __restrict__ q,
                                             u16* __restrict__ qbf,
                                             const unsigned int* __restrict__ mw,
                                             int* __restrict__ flag) {
  int i = blockIdx.x * blockDim.x + threadIdx.x;   // 524288 chunks of 8 elems
  int row = i >> 6, c = i & 63;
  int g = c >> 2, lg = c & 3;
  const float* src = q + (size_t)row * 512 + g * 32 + lg * 4;
  float4 v0 = *reinterpret_cast<const float4*>(src);
  float4 v1 = *reinterpret_cast<const float4*>(src + 16);
  u32 w0 = f2bf(v0.x) | ((u32)f2bf(v0.y) << 16);
  u32 w1 = f2bf(v0.z) | ((u32)f2bf(v0.w) << 16);
  u32 w2 = f2bf(v1.x) | ((u32)f2bf(v1.y) << 16);
  u32 w3 = f2bf(v1.z) | ((u32)f2bf(v1.w) << 16);
  uint4 out = {w0, w1, w2, w3};
  *reinterpret_cast<uint4*>(qbf + (size_t)row * 512 + c * 8) = out;

  int fB = 0, fF = 0;
  if (i < 262144) {
    unsigned int v = mw[i];
    if (v == 0x3F800000u) fF = 1;
    else if (v > 1u) fB = 1;
  }
  if (__any(fB)) { if ((threadIdx.x & 63) == 0) atomicOr(&flag[0], 1); }
  if (__any(fF)) { if ((threadIdx.x & 63) == 0) atomicOr(&flag[1], 1); }
}

// ---------------- pack weights: permutation + bf16 + grouped-eperm cols ----------
__global__ __launch_bounds__(256) void kpack(const float* __restrict__ w_in,
                                             const float* __restrict__ b_in,
                                             const float* __restrict__ w_out,
                                             u16* __restrict__ Wpack, float* __restrict__ bpack,
                                             u16* __restrict__ Wout) {
  const int T0 = 1536 * 512;           // Wpack
  const int T1 = T0 + 512 * 512;       // Wout
  const int T2 = T1 + 1536;            // bpack
  for (int i = blockIdx.x * blockDim.x + threadIdx.x; i < T2; i += gridDim.x * blockDim.x) {
    if (i < T0) {
      int n = i >> 9, d = i & 511;
      int sel = n >> 9, idx = n & 511;
      int h = idx >> 6, e = idx & 63;
      int row = h * 192 + e * 3 + sel;   // in_weight.reshape(H,64,3,D) interleave
      float v = w_in[row * 512 + d];
      if (sel == 0) v *= Q_SCALE;
      Wpack[(size_t)n * 512 + gperm(d)] = f2bf(v);
    } else if (i < T1) {
      int j = i - T0;
      int n = j >> 9, d = j & 511;
      Wout[(size_t)n * 512 + gperm(d)] = f2bf(w_out[j]);
    } else {
      int n = i - T1;
      int sel = n >> 9, idx = n & 511;
      int h = idx >> 6, e = idx & 63;
      int row = h * 192 + e * 3 + sel;
      float v = b_in[row];
      if (sel == 0) v *= Q_SCALE;
      bpack[n] = v;
    }
  }
}

// ---------------- stage one 128x64-elem K-tile pair (A and B) into LDS ----------
static __device__ __forceinline__ void stage_tile(const u16* __restrict__ A,
                                                  const u16* __restrict__ Bw,
                                                  int m0, int n0, int t,
                                                  char* tA, char* tB, int tid) {
  int w64 = tid & ~63;                      // wave base (uniform per wave)
#pragma unroll
  for (int i = 0; i < 4; i++) {
    int cl = tid + i * 256;                 // 16B chunk id, 0..1023
    int r = cl >> 3, c = cl & 7;
    size_t gofs = (size_t)r * 1024 + t * 128 + ((c ^ (r & 7)) << 4);
    gload_lds16((const char*)A + (size_t)m0 * 1024 + gofs, tA + (i * 256 + w64) * 16);
    gload_lds16((const char*)Bw + (size_t)n0 * 1024 + gofs, tB + (i * 256 + w64) * 16);
  }
}

// ---------------- tiled GEMM: C[M x N] = A[M x 512] @ B[N x 512]^T ----------------
// MODE 0: QKV projection epilogue (split Q/K/V, bf16, bias from bpack)
// MODE 1: out projection epilogue (f32 + bias)
template<int MODE>
__global__ __launch_bounds__(256) void kgemm(const u16* __restrict__ A,
                                             const u16* __restrict__ Bw,
                                             const float* __restrict__ bias,
                                             u16* __restrict__ Qb, u16* __restrict__ Kb,
                                             u16* __restrict__ Vb, float* __restrict__ outp) {
  __shared__ __align__(128) char tA[2][16384], tB[2][16384];
  int tid = threadIdx.x;
  int w = tid >> 6, lane = tid & 63;
  int lr = lane & 15, lg = lane >> 4;
  int m0 = blockIdx.x * 128, n0 = blockIdx.y * 128;
  int wr = w >> 1, wc = w & 1;

  f32x4 acc[4][4] = {};

  stage_tile(A, Bw, m0, n0, 0, tA[0], tB[0], tid);
  __syncthreads();
#pragma unroll 1
  for (int t = 0; t < 8; t++) {
    if (t < 7) stage_tile(A, Bw, m0, n0, t + 1, tA[(t + 1) & 1], tB[(t + 1) & 1], tid);
    const char* mA = tA[t & 1] + wr * 64 * 128;
    const char* mB = tB[t & 1] + wc * 64 * 128;
#pragma unroll
    for (int gg = 0; gg < 2; gg++) {
      bf16x8 af[4], bf_[4];
#pragma unroll
      for (int i = 0; i < 4; i++) af[i] = lds_frag(mA, i, gg, lr, lg);
#pragma unroll
      for (int j = 0; j < 4; j++) bf_[j] = lds_frag(mB, j, gg, lr, lg);
#pragma unroll
      for (int i = 0; i < 4; i++)
#pragma unroll
        for (int j = 0; j < 4; j++)
          acc[i][j] = __builtin_amdgcn_mfma_f32_16x16x32_bf16(af[i], bf_[j], acc[i][j], 0, 0, 0);
    }
    __syncthreads();
  }

#pragma unroll
  for (int j = 0; j < 4; j++) {
    int col = n0 + wc * 64 + j * 16 + lr;
    float bb = bias[col];
#pragma unroll
    for (int i = 0; i < 4; i++) {
#pragma unroll
      for (int jj = 0; jj < 4; jj++) {
        int row = m0 + wr * 64 + i * 16 + lg * 4 + jj;
        float val = acc[i][j][jj] + bb;
        if (MODE == 1) {
          outp[(size_t)row * 512 + col] = val;
        } else {
          u16 bv = f2bf(val);
          int b = row >> 11, l = row & 2047;
          if (col < 512) {
            int h = col >> 6, e = col & 63;
            Qb[((((size_t)(b * 8 + h)) << 11) + l) * 64 + gperm(e)] = bv;
          } else if (col < 1024) {
            int c2 = col - 512, h = c2 >> 6, e = c2 & 63;
            Kb[((((size_t)(b * 8 + h)) << 11) + l) * 64 + gperm(e)] = bv;
          } else {
            Vb[(size_t)row * 512 + gperm(col - 1024)] = bv;
          }
        }
      }
    }
  }
}

// ---------------- per-row softmax denom, swapped operands (D[k][q]) ----------------
// 4 waves x 16 q = 64 q rows/block; k-tile 64 rows, LDS 2x8KB (R12 config —
// confirmed best; (256,4) is the only spill-safe occupancy point on gfx950).
__global__ __launch_bounds__(256, 4) void kstats(const u16* __restrict__ Qb,
                                                 const u16* __restrict__ Kb,
                                                 float* __restrict__ stats) {
  __shared__ __align__(128) char tile[2][8192];
  int bh = blockIdx.x;
  int tid = threadIdx.x;
  int w = tid >> 6, lane = tid & 63;
  int lr = lane & 15, lg = lane >> 4;
  int q0 = blockIdx.y * 64 + w * 16;
  const u16* Qp = Qb + (size_t)bh * L_SZ * E_SZ;
  const u16* Kp = Kb + (size_t)bh * L_SZ * E_SZ;

  bf16x8 bq0 = qfrag(Qp, q0 + lr, 0, lg);
  bf16x8 bq1 = qfrag(Qp, q0 + lr, 1, lg);
  float s0 = 0.0f;

  stage_ktile<256, 512>(Kp, 0, tile[0], tid);
  __syncthreads();
#pragma unroll 1
  for (int t = 0; t < 32; t++) {
    if (t + 1 < 32) stage_ktile<256, 512>(Kp, (t + 1) * 64, tile[(t + 1) & 1], tid);
    const char* tl = tile[t & 1];
#pragma unroll
    for (int c = 0; c < 4; c++) {
      bf16x8 a0 = lds_frag(tl, c, 0, lr, lg);
      bf16x8 a1 = lds_frag(tl, c, 1, lr, lg);
      f32x4 d = {0.f, 0.f, 0.f, 0.f};
      d = __builtin_amdgcn_mfma_f32_16x16x32_bf16(a0, bq0, d, 0, 0, 0);
      d = __builtin_amdgcn_mfma_f32_16x16x32_bf16(a1, bq1, d, 0, 0, 0);
      s0 += fexp2(d[0]) + fexp2(d[1]) + fexp2(d[2]) + fexp2(d[3]);
    }
    __syncthreads();
  }
  s0 += __shfl_xor(s0, 16);
  s0 += __shfl_xor(s0, 32);
  if (lane < 16) stats[(size_t)bh * L_SZ + q0 + lr] = 1.0f / s0;
}

// ---------------- masks: recompute S swapped, exp2, sum heads, mask, float4 write ----
// 4 waves x 32 q = 128 q rows/block; k-tile 64, LDS 2x8KB; Q/rr prefetch; mask
// pre-packed to bits. R12-exact config (confirmed optimum after q-sweep 16/32/64
// -> 82/70/87 us and 11 structural variants). All reg accesses STATIC (rule #20).
#define KM_PACKMASK(BITS, QOFS)                                                  \
  {                                                                              \
    size_t moff = mb + (size_t)(q0 + (QOFS) + lr) * L_SZ + kb0;                  \
    if (mode == 0) {                                                             \
      _Pragma("unroll")                                                          \
      for (int c = 0; c < 4; c++) {                                              \
        int4 mi = *reinterpret_cast<const int4*>((const int*)mask + moff + c * 16 + lg * 4); \
        BITS |= (mi.x ? 1u : 0u) << (c * 4);                                     \
        BITS |= (mi.y ? 1u : 0u) << (c * 4 + 1);                                 \
        BITS |= (mi.z ? 1u : 0u) << (c * 4 + 2);                                 \
        BITS |= (mi.w ? 1u : 0u) << (c * 4 + 3);                                 \
      }                                                                          \
    } else if (mode == 1) {                                                      \
      _Pragma("unroll")                                                          \
      for (int c = 0; c < 4; c++) {                                              \
        u32 mw = *reinterpret_cast<const u32*>((const unsigned char*)mask + moff + c * 16 + lg * 4); \
        BITS |= ((mw & 0x000000FFu) ? 1u : 0u) << (c * 4);                       \
        BITS |= ((mw & 0x0000FF00u) ? 1u : 0u) << (c * 4 + 1);                   \
        BITS |= ((mw & 0x00FF0000u) ? 1u : 0u) << (c * 4 + 2);                   \
        BITS |= ((mw & 0xFF000000u) ? 1u : 0u) << (c * 4 + 3);                   \
      }                                                                          \
    } else {                                                                     \
      _Pragma("unroll")                                                          \
      for (int c = 0; c < 4; c++) {                                              \
        float4 mf = *reinterpret_cast<const float4*>((const float*)mask + moff + c * 16 + lg * 4); \
        BITS |= ((mf.x != 0.f) ? 1u : 0u) << (c * 4);                            \
        BITS |= ((mf.y != 0.f) ? 1u : 0u) << (c * 4 + 1);                        \
        BITS |= ((mf.z != 0.f) ? 1u : 0u) << (c * 4 + 2);                        \
        BITS |= ((mf.w != 0.f) ? 1u : 0u) << (c * 4 + 3);                        \
      }                                                                          \
    }                                                                            \
  }

#define KM_EPILOGUE(PACC, QOFS, BITS)                                            \
  {                                                                              \
    int q = q0 + (QOFS) + lr;                                                    \
    float* mrow = mbase_out + (size_t)q * L_SZ + kb0;                            \
    _Pragma("unroll")                                                            \
    for (int c = 0; c < 4; c++) {                                                \
      int kk = c * 16 + lg * 4;                                                  \
      f32x4 v = PACC[c];                                                         \
      if ((BITS >> (c * 4 + 0)) & 1u) v[0] = 0.f;                                \
      if ((BITS >> (c * 4 + 1)) & 1u) v[1] = 0.f;                                \
      if ((BITS >> (c * 4 + 2)) & 1u) v[2] = 0.f;                                \
      if ((BITS >> (c * 4 + 3)) & 1u) v[3] = 0.f;                                \
      *reinterpret_cast<f32x4*>(mrow + kk) = v;                                  \
    }                                                                            \
  }

__global__ __launch_bounds__(256, 4) void kmasks(const u16* __restrict__ Qb,
                                                 const u16* __restrict__ Kb,
                                                 const float* __restrict__ stats,
                                                 const void* __restrict__ mask,
                                                 const int* __restrict__ flag,
                                                 float* __restrict__ outp) {
  __shared__ __align__(128) char tile[2][8192];
  int b = blockIdx.z;
  int tid = threadIdx.x;
  int w = tid >> 6, lane = tid & 63;
  int lr = lane & 15, lg = lane >> 4;
  int q0 = blockIdx.y * 128 + w * 32;
  int kb0 = blockIdx.x * 64;
  int mode = flag[0] ? 1 : (flag[1] ? 2 : 0);
  const size_t LE = (size_t)L_SZ * E_SZ;
  size_t mb = (size_t)b * L_SZ * L_SZ;

  f32x4 P0[4] = {}, P1[4] = {};

  // prologue: stage head-0 K tile; Q frags + rr; mask bits (overlaps staging)
  stage_ktile<256, 512>(Kb + (size_t)(b * 8) * LE, kb0, tile[0], tid);
  const u16* Q0 = Qb + (size_t)(b * 8) * LE;
  bf16x8 nq0 = qfrag(Q0, q0 + lr, 0, lg);
  bf16x8 nq1 = qfrag(Q0, q0 + lr, 1, lg);
  bf16x8 nq2 = qfrag(Q0, q0 + 16 + lr, 0, lg);
  bf16x8 nq3 = qfrag(Q0, q0 + 16 + lr, 1, lg);
  float nr0 = stats[(size_t)(b * 8) * L_SZ + q0 + lr];
  float nr1 = stats[(size_t)(b * 8) * L_SZ + q0 + 16 + lr];
  u32 bits0 = 0, bits1 = 0;
  KM_PACKMASK(bits0, 0)
  KM_PACKMASK(bits1, 16)
  __syncthreads();

#pragma unroll 1
  for (int h = 0; h < 8; h++) {
    bf16x8 bq0 = nq0, bq1 = nq1, bq2 = nq2, bq3 = nq3;
    float rr0 = nr0, rr1 = nr1;
    if (h + 1 < 8) {
      stage_ktile<256, 512>(Kb + (size_t)(b * 8 + h + 1) * LE, kb0, tile[(h + 1) & 1], tid);
      const u16* Qn = Qb + (size_t)(b * 8 + h + 1) * LE;
      nq0 = qfrag(Qn, q0 + lr, 0, lg);
      nq1 = qfrag(Qn, q0 + lr, 1, lg);
      nq2 = qfrag(Qn, q0 + 16 + lr, 0, lg);
      nq3 = qfrag(Qn, q0 + 16 + lr, 1, lg);
      nr0 = stats[(size_t)(b * 8 + h + 1) * L_SZ + q0 + lr];
      nr1 = stats[(size_t)(b * 8 + h + 1) * L_SZ + q0 + 16 + lr];
    }
    const char* tl = tile[h & 1];
#pragma unroll
    for (int c = 0; c < 4; c++) {
      bf16x8 a0 = lds_frag(tl, c, 0, lr, lg);
      bf16x8 a1 = lds_frag(tl, c, 1, lr, lg);
      f32x4 d0 = {0.f, 0.f, 0.f, 0.f}, d1 = {0.f, 0.f, 0.f, 0.f};
      d0 = __builtin_amdgcn_mfma_f32_16x16x32_bf16(a0, bq0, d0, 0, 0, 0);
      d0 = __builtin_amdgcn_mfma_f32_16x16x32_bf16(a1, bq1, d0, 0, 0, 0);
      d1 = __builtin_amdgcn_mfma_f32_16x16x32_bf16(a0, bq2, d1, 0, 0, 0);
      d1 = __builtin_amdgcn_mfma_f32_16x16x32_bf16(a1, bq3, d1, 0, 0, 0);
#pragma unroll
      for (int j = 0; j < 4; j++) {
        P0[c][j] += fexp2(d0[j]) * rr0;
        P1[c][j] += fexp2(d1[j]) * rr1;
      }
    }
    __syncthreads();
  }

  float* mbase_out = outp + (size_t)B_SZ * L_SZ * D_SZ + (size_t)b * L_SZ * L_SZ;
  KM_EPILOGUE(P0, 0, bits0)
  KM_EPILOGUE(P1, 16, bits1)
}

extern "C" void kernel_launch(void* const* d_in, const int* in_sizes, int n_in,
                              void* d_out, int out_size, void* d_ws, size_t ws_size,
                              hipStream_t stream) {
  (void)in_sizes; (void)n_in; (void)out_size; (void)ws_size;
  const float* q     = (const float*)d_in[0];
  const void*  mask  = d_in[1];
  const float* w_in  = (const float*)d_in[2];
  const float* b_in  = (const float*)d_in[3];
  const float* w_out = (const float*)d_in[4];
  const float* b_out = (const float*)d_in[5];
  float* outp = (float*)d_out;
  char* ws = (char*)d_ws;

  int*    flag  = (int*)(ws + WS_FLAG);
  u16*    Wpack = (u16*)(ws + WS_WPACK);
  float*  bpack = (float*)(ws + WS_BPACK);
  u16*    Wout  = (u16*)(ws + WS_WOUT);
  u16*    qbf   = (u16*)(ws + WS_QBF);
  u16*    Qb    = (u16*)(ws + WS_Q);
  u16*    Kb    = (u16*)(ws + WS_K);
  u16*    Vb    = (u16*)(ws + WS_V);
  float*  stats = (float*)(ws + WS_STATS);

  hipMemsetAsync(flag, 0, 16, stream);
  hipLaunchKernelGGL(kcast, dim3(2048), dim3(256), 0, stream, q, qbf,
                     (const unsigned int*)mask, flag);
  hipLaunchKernelGGL(kpack, dim3(2048), dim3(256), 0, stream, w_in, b_in, w_out,
                     Wpack, bpack, Wout);
  hipLaunchKernelGGL((kgemm<0>), dim3(64, 12), dim3(256), 0, stream,
                     qbf, Wpack, bpack, Qb, Kb, Vb, (float*)nullptr);
  hipLaunchKernelGGL((kgemm<1>), dim3(64, 4), dim3(256), 0, stream,
                     Vb, Wout, b_out, (u16*)nullptr, (u16*)nullptr, (u16*)nullptr, outp);
  hipLaunchKernelGGL(kstats, dim3(32, 32), dim3(256), 0, stream, Qb, Kb, stats);
  hipLaunchKernelGGL(kmasks, dim3(32, 16, 4), dim3(256), 0, stream, Qb, Kb, stats, mask, flag, outp);
}